// Round 1
// baseline (9.421 us; speedup 1.0000x reference)
//
#include <hip/hip_runtime.h>

// NLL loss with ignore_index=0:
//   loss = -sum_{i: target[i] != 0} output[i, target[i]]
// output: [N, V] fp32, target: [N] int (harness converts int64 -> int32)
// Single-block deterministic reduction: 1024 threads, each gathers N/1024 rows,
// wave shuffle-reduce (width 64) -> LDS across 16 waves -> one store.

#define BLK 1024

__global__ __launch_bounds__(BLK) void myNLLLoss_7962869367387_kernel(
    const float* __restrict__ out,
    const int* __restrict__ tgt,
    float* __restrict__ loss,
    int N, long long V)
{
    const int tid = threadIdx.x;
    float s = 0.0f;
    for (int i = tid; i < N; i += BLK) {
        const int t = tgt[i];
        if (t != 0) {
            s += out[(long long)i * V + (long long)t];
        }
    }

    // wave-level reduce (wave = 64 lanes on CDNA)
    #pragma unroll
    for (int off = 32; off > 0; off >>= 1) {
        s += __shfl_down(s, off, 64);
    }

    __shared__ float wsum[BLK / 64];
    const int lane = tid & 63;
    const int wave = tid >> 6;
    if (lane == 0) wsum[wave] = s;
    __syncthreads();

    if (wave == 0) {
        float v = (lane < (BLK / 64)) ? wsum[lane] : 0.0f;
        #pragma unroll
        for (int off = 8; off > 0; off >>= 1) {
            v += __shfl_down(v, off, 64);
        }
        if (lane == 0) *loss = -v;
    }
}

extern "C" void kernel_launch(void* const* d_in, const int* in_sizes, int n_in,
                              void* d_out, int out_size, void* d_ws, size_t ws_size,
                              hipStream_t stream) {
    const float* out = (const float*)d_in[0];
    const int*   tgt = (const int*)d_in[1];
    float* loss = (float*)d_out;

    const int N = in_sizes[1];                          // 4096
    const long long V = (long long)(in_sizes[0] / N);   // 50257

    hipLaunchKernelGGL(myNLLLoss_7962869367387_kernel,
                       dim3(1), dim3(BLK), 0, stream,
                       out, tgt, loss, N, V);
}